// Round 12
// baseline (255.664 us; speedup 1.0000x reference)
//
#include <hip/hip_runtime.h>
#include <hip/hip_bf16.h>

#define N_NODES 50000
#define N_EDGES 600000
#define DIM_H   128
#define NPAD    50048   // N_NODES rounded up to 128 (DMA-safe zero tail)
#define NB_SCAN 196     // ceil(N_NODES / 256)

typedef __attribute__((ext_vector_type(8))) short bf16x8;   // 8 bf16 = 4 VGPRs
typedef __attribute__((ext_vector_type(4))) float f32x4;    // MFMA acc
typedef __attribute__((ext_vector_type(4))) short short4v;

__device__ __forceinline__ short f2bs(float f) {
    __hip_bfloat16 h = __float2bfloat16(f);   // RNE
    return *reinterpret_cast<short*>(&h);
}
__device__ __forceinline__ float bs2f(short s) {
    unsigned u = ((unsigned)(unsigned short)s) << 16;
    return __builtin_bit_cast(float, u);
}
__device__ __forceinline__ float sigm(float x) { return 1.f / (1.f + __expf(-x)); }
__device__ __forceinline__ float tanh_f(float x) {
    return 2.f / (1.f + __expf(-2.f * x)) - 1.f;   // saturates correctly
}
__device__ __forceinline__ unsigned pk2(float a, float b) {
    return ((unsigned)(unsigned short)f2bs(b) << 16) | (unsigned)(unsigned short)f2bs(a);
}
__device__ __forceinline__ float unlo(unsigned u) { return bs2f((short)(u & 0xffffu)); }
__device__ __forceinline__ float unhi(unsigned u) { return bs2f((short)(u >> 16)); }

// global -> LDS async DMA, 16 B per lane; LDS dst is wave-uniform base + lane*16.
__device__ __forceinline__ void dma16(const void* g, const void* lds_uniform) {
    __builtin_amdgcn_global_load_lds(
        (const __attribute__((address_space(1))) void*)g,
        (__attribute__((address_space(3))) void*)(unsigned)(unsigned long long)lds_uniform,
        16, 0, 0);
}

// ---------------------------------------------------------------------------
// K0: prep — ZERO-ONLY (cnt/colsum/nodes padded tail).
// ---------------------------------------------------------------------------
__global__ __launch_bounds__(256) void prep_k(int* __restrict__ cnt,
                                              float* __restrict__ colsum,
                                              short* __restrict__ nodesTail) {
    int i = blockIdx.x * 256 + threadIdx.x;
    if (i < N_NODES) cnt[i] = 0;
    if (i < 128) colsum[i] = 0.f;
    if (i < 1536) {           // 48 rows x 128 shorts = 6144 shorts = 1536 short4
        short4v z = {0, 0, 0, 0};
        *(short4v*)(nodesTail + i * 4) = z;
    }
}

// ---------------------------------------------------------------------------
// K1: MERGED colsum/nodesB-convert + edge histogram (independent work; the
// latency-bound hist atomics hide under the BW-bound colsum stream).
// ---------------------------------------------------------------------------
__global__ __launch_bounds__(256) void ch_k(const float* __restrict__ nodes,
                                            float* __restrict__ colsum,
                                            short* __restrict__ nodesB,
                                            const int* __restrict__ edst,
                                            int* __restrict__ cnt) {
    const int tid = threadIdx.x;
    // ---- hist: 4 edges/thread, int4 loads (fire-and-forget atomics) ----
    {
        int e = (blockIdx.x * 256 + tid) * 4;
        if (e + 3 < N_EDGES) {
            int4 d = *(const int4*)(edst + e);
            atomicAdd(&cnt[d.x], 1); atomicAdd(&cnt[d.y], 1);
            atomicAdd(&cnt[d.z], 1); atomicAdd(&cnt[d.w], 1);
        } else {
            for (; e < N_EDGES; ++e) atomicAdd(&cnt[edst[e]], 1);
        }
    }
    // ---- colsum + bf16 conversion (grid-stride over rows) ----
    __shared__ float red[8][128];
    const int cg = tid & 31;
    const int rl = tid >> 5;
    float4 acc = {0.f, 0.f, 0.f, 0.f};
    for (int r = blockIdx.x * 8 + rl; r < N_NODES; r += gridDim.x * 8) {
        float4 v = *(const float4*)(nodes + (size_t)r * DIM_H + cg * 4);
        acc.x += v.x; acc.y += v.y; acc.z += v.z; acc.w += v.w;
        *(short4v*)(nodesB + (size_t)r * DIM_H + cg * 4) =
            (short4v){f2bs(v.x), f2bs(v.y), f2bs(v.z), f2bs(v.w)};
    }
    *(float4*)&red[rl][cg * 4] = acc;
    __syncthreads();
    if (tid < 128) {
        float s = 0.f;
#pragma unroll
        for (int i = 0; i < 8; ++i) s += red[i][tid];
        unsafeAtomicAdd(&colsum[tid], s);
    }
}

// ---------------------------------------------------------------------------
// K2: single-kernel exclusive scan (+ absorbed weight bf16 conversion — the
// cvt is independent grid-stride work that overlaps the offset-sum L2 reads).
// ---------------------------------------------------------------------------
__global__ __launch_bounds__(256) void scan_k(const int* __restrict__ cnt,
                                              int* __restrict__ rowptr,
                                              int* __restrict__ pos,
                                              const float* __restrict__ wmsg,
                                              const float* __restrict__ wih,
                                              const float* __restrict__ whh,
                                              short* __restrict__ wmsgB,
                                              short* __restrict__ wihB,
                                              short* __restrict__ whhB) {
    const int b = blockIdx.x, t = threadIdx.x;
    const int lane = t & 63, w = t >> 6;
    __shared__ int red[4];
    __shared__ int wsum[4];

    // ---- absorbed weight conversion (grid-stride) ----
    {
        const int gid = b * 256 + t;
        const int gsz = NB_SCAN * 256;     // 50176 threads
        for (int i = gid; i < 49152; i += gsz) {
            wihB[i] = f2bs(wih[i]);
            whhB[i] = f2bs(whh[i]);
        }
        if (gid < 16384) wmsgB[gid] = f2bs(wmsg[gid]);
    }

    // ---- global offset = sum cnt[0 .. b*256) ----
    int tot = 0;
    const int lim = b * 256;                 // multiple of 256 (and of 4)
    for (int i = t * 4; i < lim; i += 1024) {
        int4 v = *(const int4*)(cnt + i);
        tot += (v.x + v.y) + (v.z + v.w);
    }
#pragma unroll
    for (int o = 32; o; o >>= 1) tot += __shfl_xor(tot, o, 64);
    if (lane == 0) red[w] = tot;
    __syncthreads();
    const int offset = red[0] + red[1] + red[2] + red[3];

    // ---- own-chunk exclusive scan ----
    int i = b * 256 + t;
    int v = (i < N_NODES) ? cnt[i] : 0;
    int x = v;
#pragma unroll
    for (int o = 1; o < 64; o <<= 1) {
        int y = __shfl_up(x, o, 64);
        if (lane >= o) x += y;
    }
    if (lane == 63) wsum[w] = x;
    __syncthreads();
    int woff = 0;
#pragma unroll
    for (int j = 0; j < 4; ++j)
        if (j < w) woff += wsum[j];
    int excl = offset + woff + (x - v);
    if (i < N_NODES) { rowptr[i] = excl; pos[i] = excl; }
    if (i == N_NODES - 1) rowptr[N_NODES] = excl + v;
}

__global__ __launch_bounds__(256) void reorder_k(const int* __restrict__ esrc,
                                                 const int* __restrict__ edst,
                                                 int* __restrict__ pos,
                                                 int* __restrict__ ssrc) {
    int e = (blockIdx.x * 256 + threadIdx.x) * 4;
    if (e + 3 < N_EDGES) {
        int4 s = *(const int4*)(esrc + e);
        int4 d = *(const int4*)(edst + e);
        ssrc[atomicAdd(&pos[d.x], 1)] = s.x;
        ssrc[atomicAdd(&pos[d.y], 1)] = s.y;
        ssrc[atomicAdd(&pos[d.z], 1)] = s.z;
        ssrc[atomicAdd(&pos[d.w], 1)] = s.w;
    } else {
        for (; e < N_EDGES; ++e) {
            int p = atomicAdd(&pos[edst[e]], 1);
            ssrc[p] = esrc[e];
        }
    }
}

// ---------------------------------------------------------------------------
// K3: FULLY FUSED, wave-local, 8-wave / 128-row edition + IN-KERNEL AGGREGATE.
// The aggregate kernel is absorbed into the prologue: each wave gathers the
// neighbor sums for its own 16-row strip (4 rows concurrently via 16-lane
// groups, 16 B/lane, 8 edge-rows in flight), rounds to bf16 into its own Ms
// strip using the EPI1 swizzle (proven wave-local LDS write->fragment-read
// pattern), then reads aggF fragments back. aggB (25.6 MB HBM round-trip)
// and the separate aggregate launch are eliminated; the gather overlaps the
// chunk-0 weight DMA. No setprio (round-11: neutral-to-negative).
// ---------------------------------------------------------------------------
__global__ __launch_bounds__(512) void fused_k(const short* __restrict__ nodesB,
                                               const int* __restrict__ rowptr,
                                               const int* __restrict__ ssrc,
                                               const short* __restrict__ wmsgB,
                                               const short* __restrict__ wihB,
                                               const short* __restrict__ whhB,
                                               const float* __restrict__ bmsg,
                                               const float* __restrict__ bih,
                                               const float* __restrict__ bhh,
                                               const int* __restrict__ deg,
                                               const float* __restrict__ colsum,
                                               const float* __restrict__ gamma,
                                               const float* __restrict__ beta,
                                               float* __restrict__ out) {
    __shared__ short Ms[128 * 128];       // agg tile -> (in place) msgin tile
    __shared__ short Wb[2][64 * 128];     // double-buffered weight chunk
    __shared__ float biasL[1280];         // bih|bhh|bmsg|cs|gamma|beta

    const int tid = threadIdx.x;
    const int lane = tid & 63, w = tid >> 6;        // w = 0..7
    const int m0 = blockIdx.x * 128;
    const int r16 = lane & 15, qh = lane >> 4;      // lane = 16*qh + r16
    const int wm = w * 16;                           // wave's 16-row strip
    const float invN = 1.0f / N_NODES;

    // weight chunk staging: 64 rows x 128 cols, XOR-swizzled 16B granules.
    // 8 waves x 2 dma16 each cover the 16 KB chunk.
#define STAGE_W(SRC, ROW0, BUF) do {                                         \
    _Pragma("unroll") for (int it = 0; it < 2; ++it) {                       \
        int c = w * 2 + it;                                                  \
        int s = c * 64 + lane;                                               \
        int r = s >> 4, q = s & 15;                                          \
        int g = q ^ (r & 15);                                                \
        dma16((SRC) + (((size_t)((ROW0) + r)) << 7) + (g << 3),              \
              &Wb[BUF][0] + (size_t)c * 512);                                \
    } } while (0)

    STAGE_W(wmsgB, 0, 0);                 // chunk 0 DMA flies under the gather

    // ---- prologue A: biases -> LDS ----
    if (tid < 384) {
        biasL[tid]       = bih[tid];
        biasL[384 + tid] = bhh[tid];
    }
    if (tid < 128) {
        biasL[768  + tid] = bmsg[tid];
        biasL[896  + tid] = colsum[tid] * invN;
        biasL[1024 + tid] = gamma[tid];
        biasL[1152 + tid] = beta[tid];
    }

    // ---- prologue B: IN-KERNEL AGGREGATE into Ms (wave-local strip) ----
    // 4 rows concurrently: group qh handles row wm + i*4 + qh; lane r16 owns
    // cols [r16*8, r16*8+8). Writes use the EPI1 swizzle: slot = col8 ^ (lr&15).
#pragma unroll
    for (int i = 0; i < 4; ++i) {
        const int lr = wm + i * 4 + qh;
        const int n = m0 + lr;
        int s0 = 0, s1 = 0;
        if (n < N_NODES) { s0 = rowptr[n]; s1 = rowptr[n + 1]; }
        float accf[8] = {0.f, 0.f, 0.f, 0.f, 0.f, 0.f, 0.f, 0.f};
        int e = s0;
        for (; e + 7 < s1; e += 8) {          // 8 edge-rows in flight
            int4 ia = *(const int4*)(ssrc + e);
            int4 ib = *(const int4*)(ssrc + e + 4);
            bf16x8 va = *(const bf16x8*)(nodesB + (size_t)ia.x * DIM_H + r16 * 8);
            bf16x8 vb = *(const bf16x8*)(nodesB + (size_t)ia.y * DIM_H + r16 * 8);
            bf16x8 vc = *(const bf16x8*)(nodesB + (size_t)ia.z * DIM_H + r16 * 8);
            bf16x8 vd = *(const bf16x8*)(nodesB + (size_t)ia.w * DIM_H + r16 * 8);
            bf16x8 ve = *(const bf16x8*)(nodesB + (size_t)ib.x * DIM_H + r16 * 8);
            bf16x8 vf = *(const bf16x8*)(nodesB + (size_t)ib.y * DIM_H + r16 * 8);
            bf16x8 vg = *(const bf16x8*)(nodesB + (size_t)ib.z * DIM_H + r16 * 8);
            bf16x8 vh = *(const bf16x8*)(nodesB + (size_t)ib.w * DIM_H + r16 * 8);
#pragma unroll
            for (int k = 0; k < 8; ++k)
                accf[k] += ((bs2f(va[k]) + bs2f(vb[k])) + (bs2f(vc[k]) + bs2f(vd[k])))
                         + ((bs2f(ve[k]) + bs2f(vf[k])) + (bs2f(vg[k]) + bs2f(vh[k])));
        }
        for (; e < s1; ++e) {
            int sa = ssrc[e];
            bf16x8 va = *(const bf16x8*)(nodesB + (size_t)sa * DIM_H + r16 * 8);
#pragma unroll
            for (int k = 0; k < 8; ++k) accf[k] += bs2f(va[k]);
        }
        const int slot = r16 ^ (lr & 15);
        uint4 ov;
        ov.x = pk2(accf[0], accf[1]);
        ov.y = pk2(accf[2], accf[3]);
        ov.z = pk2(accf[4], accf[5]);
        ov.w = pk2(accf[6], accf[7]);
        *(uint4*)&Ms[lr * 128 + slot * 8] = ov;
    }

    // ---- prologue C: A-fragments (aggF from Ms, nodF from global) + deg ----
    bf16x8 aggF[4], nodF[4], msgF[4];
    const size_t rowA = (size_t)(m0 + wm + r16) * 128;
#pragma unroll
    for (int kt = 0; kt < 4; ++kt) {
        int kg = (kt << 2) + qh;
        aggF[kt] = *(const bf16x8*)&Ms[(wm + r16) * 128 + ((kg ^ r16) << 3)];
        nodF[kt] = *(const bf16x8*)(nodesB + rowA + (size_t)kg * 8);
    }
    int4 dgi = *(const int4*)(deg + m0 + wm + qh * 4);

    f32x4 acc[2][4];
    unsigned rp[2][4][2], inp[2][4][2], np_[2][4][2];

#define CHUNK(BUF, AF, H, RST) do {                                          \
    _Pragma("unroll") for (int kt = 0; kt < 4; ++kt) {                       \
        const int sq = (((kt << 2) + qh) ^ r16) << 3;                        \
        bf16x8 b0 = *(const bf16x8*)&Wb[BUF][(r16     ) * 128 + sq];         \
        bf16x8 b1 = *(const bf16x8*)&Wb[BUF][(r16 + 16) * 128 + sq];         \
        bf16x8 b2 = *(const bf16x8*)&Wb[BUF][(r16 + 32) * 128 + sq];         \
        bf16x8 b3 = *(const bf16x8*)&Wb[BUF][(r16 + 48) * 128 + sq];         \
        f32x4 z4 = {0.f, 0.f, 0.f, 0.f};                                     \
        acc[H][0] = __builtin_amdgcn_mfma_f32_16x16x32_bf16(                 \
            AF[kt], b0, ((RST) && kt == 0) ? z4 : acc[H][0], 0, 0, 0);       \
        acc[H][1] = __builtin_amdgcn_mfma_f32_16x16x32_bf16(                 \
            AF[kt], b1, ((RST) && kt == 0) ? z4 : acc[H][1], 0, 0, 0);       \
        acc[H][2] = __builtin_amdgcn_mfma_f32_16x16x32_bf16(                 \
            AF[kt], b2, ((RST) && kt == 0) ? z4 : acc[H][2], 0, 0, 0);       \
        acc[H][3] = __builtin_amdgcn_mfma_f32_16x16x32_bf16(                 \
            AF[kt], b3, ((RST) && kt == 0) ? z4 : acc[H][3], 0, 0, 0);       \
    } } while (0)

    // ---------------- pipelined chunk sequence (round-4 schedule) ----------
    __syncthreads(); STAGE_W(wmsgB,  64, 1); CHUNK(0, aggF, 0, 1);   // c0
    __syncthreads(); STAGE_W(wihB,    0, 0); CHUNK(1, aggF, 1, 1);   // c1

    // EPI1: msgin = acc + deg*bmsg + colsum/N -> bf16 -> Ms, read back msgF
    {
        float dgf[4];
        dgf[0] = (m0 + wm + qh * 4 + 0 < N_NODES) ? (float)dgi.x : 0.f;
        dgf[1] = (m0 + wm + qh * 4 + 1 < N_NODES) ? (float)dgi.y : 0.f;
        dgf[2] = (m0 + wm + qh * 4 + 2 < N_NODES) ? (float)dgi.z : 0.f;
        dgf[3] = (m0 + wm + qh * 4 + 3 < N_NODES) ? (float)dgi.w : 0.f;
#pragma unroll
        for (int h = 0; h < 2; ++h)
#pragma unroll
            for (int j = 0; j < 4; ++j) {
                int c = h * 64 + j * 16 + r16;
                float bm = biasL[768 + c], cs = biasL[896 + c];
#pragma unroll
                for (int rr = 0; rr < 4; ++rr) {
                    int lr = wm + qh * 4 + rr;
                    float v = acc[h][j][rr] + dgf[rr] * bm + cs;
                    int slot = (c >> 3) ^ (lr & 15);
                    Ms[lr * 128 + slot * 8 + (c & 7)] = f2bs(v);
                }
            }
#pragma unroll
        for (int kt = 0; kt < 4; ++kt) {
            int kg = (kt << 2) + qh;
            msgF[kt] = *(const bf16x8*)&Ms[(wm + r16) * 128 + ((kg ^ r16) << 3)];
        }
    }

    __syncthreads(); STAGE_W(wihB,   64, 1); CHUNK(0, msgF, 0, 1);   // c2
    __syncthreads(); STAGE_W(whhB,    0, 0); CHUNK(1, msgF, 1, 1);   // c3
    __syncthreads(); STAGE_W(whhB,   64, 1); CHUNK(0, nodF, 0, 0);   // c4
    __syncthreads(); STAGE_W(wihB,  256, 0); CHUNK(1, nodF, 1, 0);   // c5
    // EPI2: r gate
#pragma unroll
    for (int h = 0; h < 2; ++h)
#pragma unroll
        for (int j = 0; j < 4; ++j) {
            int c = h * 64 + j * 16 + r16;
            float b0 = biasL[c] + biasL[384 + c];
            rp[h][j][0] = pk2(sigm(acc[h][j][0] + b0), sigm(acc[h][j][1] + b0));
            rp[h][j][1] = pk2(sigm(acc[h][j][2] + b0), sigm(acc[h][j][3] + b0));
        }

    __syncthreads(); STAGE_W(wihB,  320, 1); CHUNK(0, msgF, 0, 1);   // c6
    __syncthreads(); STAGE_W(whhB,  256, 0); CHUNK(1, msgF, 1, 1);   // c7
    // EPI3: i_n
#pragma unroll
    for (int h = 0; h < 2; ++h)
#pragma unroll
        for (int j = 0; j < 4; ++j) {
            int c = h * 64 + j * 16 + r16;
            float bi = biasL[256 + c];
            inp[h][j][0] = pk2(acc[h][j][0] + bi, acc[h][j][1] + bi);
            inp[h][j][1] = pk2(acc[h][j][2] + bi, acc[h][j][3] + bi);
        }

    __syncthreads(); STAGE_W(whhB,  320, 1); CHUNK(0, nodF, 0, 1);   // c8
    __syncthreads(); STAGE_W(wihB,  128, 0); CHUNK(1, nodF, 1, 1);   // c9
    // EPI4: n = tanh(i_n + r * h_n)
#pragma unroll
    for (int h = 0; h < 2; ++h)
#pragma unroll
        for (int j = 0; j < 4; ++j) {
            int c = h * 64 + j * 16 + r16;
            float bh = biasL[640 + c];
            float n0 = tanh_f(unlo(inp[h][j][0]) + unlo(rp[h][j][0]) * (acc[h][j][0] + bh));
            float n1 = tanh_f(unhi(inp[h][j][0]) + unhi(rp[h][j][0]) * (acc[h][j][1] + bh));
            float n2 = tanh_f(unlo(inp[h][j][1]) + unlo(rp[h][j][1]) * (acc[h][j][2] + bh));
            float n3 = tanh_f(unhi(inp[h][j][1]) + unhi(rp[h][j][1]) * (acc[h][j][3] + bh));
            np_[h][j][0] = pk2(n0, n1);
            np_[h][j][1] = pk2(n2, n3);
        }

    __syncthreads(); STAGE_W(wihB,  192, 1); CHUNK(0, msgF, 0, 1);   // c10
    __syncthreads(); STAGE_W(whhB,  128, 0); CHUNK(1, msgF, 1, 1);   // c11
    __syncthreads(); STAGE_W(whhB,  192, 1); CHUNK(0, nodF, 0, 0);   // c12
    __syncthreads();                         CHUNK(1, nodF, 1, 0);   // c13

    // EPI5: z; h' = (1-z)*n + z*h  (h from global bf16 nodes, L1-hot)
#pragma unroll
    for (int h = 0; h < 2; ++h)
#pragma unroll
        for (int j = 0; j < 4; ++j) {
            int c = h * 64 + j * 16 + r16;
            float b1 = biasL[128 + c] + biasL[512 + c];
#pragma unroll
            for (int rr = 0; rr < 4; ++rr) {
                int lr = wm + qh * 4 + rr;
                float hv = bs2f(nodesB[(size_t)(m0 + lr) * 128 + c]);
                float z = sigm(acc[h][j][rr] + b1);
                float nv = (rr & 1) ? unhi(np_[h][j][rr >> 1]) : unlo(np_[h][j][rr >> 1]);
                acc[h][j][rr] = (1.f - z) * nv + z * hv;   // acc := h_next
            }
        }

    // ---- LayerNorm (wave-local: each row lives in one 16-lane group) ----
#pragma unroll
    for (int rr = 0; rr < 4; ++rr) {
        float s = 0.f, q2 = 0.f;
#pragma unroll
        for (int h = 0; h < 2; ++h)
#pragma unroll
            for (int j = 0; j < 4; ++j) {
                float v = acc[h][j][rr];
                s += v; q2 += v * v;
            }
#pragma unroll
        for (int o = 1; o < 16; o <<= 1) {
            s  += __shfl_xor(s, o, 64);
            q2 += __shfl_xor(q2, o, 64);
        }
        int lr = wm + qh * 4 + rr;
        int gm = m0 + lr;
        float mu = s * (1.0f / DIM_H);
        float var = q2 * (1.0f / DIM_H) - mu * mu;
        float rstd = rsqrtf(var + 1e-5f);
        if (gm < N_NODES) {
#pragma unroll
            for (int h = 0; h < 2; ++h)
#pragma unroll
                for (int j = 0; j < 4; ++j) {
                    int c = h * 64 + j * 16 + r16;
                    int slot = (c >> 3) ^ (lr & 15);
                    float resid = bs2f(Ms[lr * 128 + slot * 8 + (c & 7)])
                                - biasL[896 + c];
                    out[(size_t)gm * DIM_H + c] =
                        biasL[1024 + c] * (acc[h][j][rr] - mu) * rstd
                        + biasL[1152 + c] + resid;
                }
        }
    }
#undef CHUNK
#undef STAGE_W
}

// ---------------------------------------------------------------------------
extern "C" void kernel_launch(void* const* d_in, const int* in_sizes, int n_in,
                              void* d_out, int out_size, void* d_ws, size_t ws_size,
                              hipStream_t stream) {
    const float* nodes = (const float*)d_in[0];
    const float* Wmsg  = (const float*)d_in[1];
    const float* bmsg  = (const float*)d_in[2];
    const float* wih   = (const float*)d_in[3];
    const float* whh   = (const float*)d_in[4];
    const float* bih   = (const float*)d_in[5];
    const float* bhh   = (const float*)d_in[6];
    const float* gamma = (const float*)d_in[7];
    const float* beta  = (const float*)d_in[8];
    const int* esrc = (const int*)d_in[9];
    const int* edst = (const int*)d_in[10];
    float* out = (float*)d_out;

    // workspace layout (~16 MB; aggB eliminated by in-fused aggregation)
    char* ws = (char*)d_ws;
    short* nodesB = (short*)ws;                        // NPAD*256 B = 12,812,288
    short* wmsgB  = (short*)(ws + 12812288);           // 32 KB
    short* wihB   = (short*)(ws + 12845056);           // 96 KB
    short* whhB   = (short*)(ws + 12943360);           // 96 KB
    float* colsum = (float*)(ws + 13041664);           // 512 B
    int*   cnt    = (int*)(ws + 13042176);             // 200 KB (degree after hist)
    int*   rowptr = (int*)(ws + 13242176);             // 200 KB + 4 (+pad)
    int*   pos    = (int*)(ws + 13442192);             // 200 KB
    int*   ssrc   = (int*)(ws + 13642192);             // 2.4 MB -> end ~16.0 MB

    short* nodesTail = nodesB + (size_t)N_NODES * DIM_H;

    prep_k<<<NB_SCAN, 256, 0, stream>>>(cnt, colsum, nodesTail);

    const int EB4 = (N_EDGES / 4 + 255) / 256;   // 586
    ch_k<<<EB4, 256, 0, stream>>>(nodes, colsum, nodesB, edst, cnt);
    scan_k<<<NB_SCAN, 256, 0, stream>>>(cnt, rowptr, pos,
                                        Wmsg, wih, whh, wmsgB, wihB, whhB);
    reorder_k<<<EB4, 256, 0, stream>>>(esrc, edst, pos, ssrc);

    const int MB = (N_NODES + 127) / 128;   // 391
    fused_k<<<MB, 512, 0, stream>>>(nodesB, rowptr, ssrc, wmsgB, wihB, whhB,
                                    bmsg, bih, bhh, cnt, colsum, gamma, beta, out);
}

// Round 13
// 236.094 us; speedup vs baseline: 1.0829x; 1.0829x over previous
//
#include <hip/hip_runtime.h>
#include <hip/hip_bf16.h>

#define N_NODES 50000
#define N_EDGES 600000
#define DIM_H   128
#define NPAD    50048   // N_NODES rounded up to 128 (DMA-safe zero tail)
#define NB_SCAN 196     // ceil(N_NODES / 256)

typedef __attribute__((ext_vector_type(8))) short bf16x8;   // 8 bf16 = 4 VGPRs
typedef __attribute__((ext_vector_type(4))) float f32x4;    // MFMA acc
typedef __attribute__((ext_vector_type(4))) short short4v;

__device__ __forceinline__ short f2bs(float f) {
    __hip_bfloat16 h = __float2bfloat16(f);   // RNE
    return *reinterpret_cast<short*>(&h);
}
__device__ __forceinline__ float bs2f(short s) {
    unsigned u = ((unsigned)(unsigned short)s) << 16;
    return __builtin_bit_cast(float, u);
}
__device__ __forceinline__ float sigm(float x) { return 1.f / (1.f + __expf(-x)); }
__device__ __forceinline__ float tanh_f(float x) {
    return 2.f / (1.f + __expf(-2.f * x)) - 1.f;   // saturates correctly
}
__device__ __forceinline__ unsigned pk2(float a, float b) {
    return ((unsigned)(unsigned short)f2bs(b) << 16) | (unsigned)(unsigned short)f2bs(a);
}
__device__ __forceinline__ float unlo(unsigned u) { return bs2f((short)(u & 0xffffu)); }
__device__ __forceinline__ float unhi(unsigned u) { return bs2f((short)(u >> 16)); }

// global -> LDS async DMA, 16 B per lane; LDS dst is wave-uniform base + lane*16.
__device__ __forceinline__ void dma16(const void* g, const void* lds_uniform) {
    __builtin_amdgcn_global_load_lds(
        (const __attribute__((address_space(1))) void*)g,
        (__attribute__((address_space(3))) void*)(unsigned)(unsigned long long)lds_uniform,
        16, 0, 0);
}

// ---------------------------------------------------------------------------
// K0: prep — weight bf16 conversion + zero cnt/colsum/padded-tails
// ---------------------------------------------------------------------------
__global__ __launch_bounds__(256) void prep_k(const float* __restrict__ wmsg,
                                              const float* __restrict__ wih,
                                              const float* __restrict__ whh,
                                              short* __restrict__ wmsgB,
                                              short* __restrict__ wihB,
                                              short* __restrict__ whhB,
                                              int* __restrict__ cnt,
                                              float* __restrict__ colsum,
                                              short* __restrict__ aggTail,
                                              short* __restrict__ nodesTail) {
    int i = blockIdx.x * 256 + threadIdx.x;
    if (i < 16384) wmsgB[i] = f2bs(wmsg[i]);
    if (i < 49152) { wihB[i] = f2bs(wih[i]); whhB[i] = f2bs(whh[i]); }
    if (i < N_NODES) cnt[i] = 0;
    if (i < 128) colsum[i] = 0.f;
    if (i < 1536) {           // 48 rows x 128 shorts = 6144 shorts = 1536 short4
        short4v z = {0, 0, 0, 0};
        *(short4v*)(aggTail   + i * 4) = z;
        *(short4v*)(nodesTail + i * 4) = z;
    }
}

// ---------------------------------------------------------------------------
// K1: MERGED colsum/nodesB-convert + edge histogram (independent work; the
// latency-bound hist atomics hide under the BW-bound colsum stream).
// ---------------------------------------------------------------------------
__global__ __launch_bounds__(256) void ch_k(const float* __restrict__ nodes,
                                            float* __restrict__ colsum,
                                            short* __restrict__ nodesB,
                                            const int* __restrict__ edst,
                                            int* __restrict__ cnt) {
    const int tid = threadIdx.x;
    // ---- hist: 4 edges/thread, int4 loads (fire-and-forget atomics) ----
    {
        int e = (blockIdx.x * 256 + tid) * 4;
        if (e + 3 < N_EDGES) {
            int4 d = *(const int4*)(edst + e);
            atomicAdd(&cnt[d.x], 1); atomicAdd(&cnt[d.y], 1);
            atomicAdd(&cnt[d.z], 1); atomicAdd(&cnt[d.w], 1);
        } else {
            for (; e < N_EDGES; ++e) atomicAdd(&cnt[edst[e]], 1);
        }
    }
    // ---- colsum + bf16 conversion (grid-stride over rows) ----
    __shared__ float red[8][128];
    const int cg = tid & 31;
    const int rl = tid >> 5;
    float4 acc = {0.f, 0.f, 0.f, 0.f};
    for (int r = blockIdx.x * 8 + rl; r < N_NODES; r += gridDim.x * 8) {
        float4 v = *(const float4*)(nodes + (size_t)r * DIM_H + cg * 4);
        acc.x += v.x; acc.y += v.y; acc.z += v.z; acc.w += v.w;
        *(short4v*)(nodesB + (size_t)r * DIM_H + cg * 4) =
            (short4v){f2bs(v.x), f2bs(v.y), f2bs(v.z), f2bs(v.w)};
    }
    *(float4*)&red[rl][cg * 4] = acc;
    __syncthreads();
    if (tid < 128) {
        float s = 0.f;
#pragma unroll
        for (int i = 0; i < 8; ++i) s += red[i][tid];
        unsafeAtomicAdd(&colsum[tid], s);
    }
}

// ---------------------------------------------------------------------------
// K2: single-kernel exclusive scan (replaces bsum_k + scan2_k).
// Each block b computes its global offset DIRECTLY from cnt[0 .. b*256)
// (int4 L2-hot reads, <=195 KB/block, ~20 MB chip-wide) then scans its chunk.
// ---------------------------------------------------------------------------
__global__ __launch_bounds__(256) void scan_k(const int* __restrict__ cnt,
                                              int* __restrict__ rowptr,
                                              int* __restrict__ pos) {
    const int b = blockIdx.x, t = threadIdx.x;
    const int lane = t & 63, w = t >> 6;
    __shared__ int red[4];
    __shared__ int wsum[4];

    // ---- global offset = sum cnt[0 .. b*256) ----
    int tot = 0;
    const int lim = b * 256;                 // multiple of 256 (and of 4)
    for (int i = t * 4; i < lim; i += 1024) {
        int4 v = *(const int4*)(cnt + i);
        tot += (v.x + v.y) + (v.z + v.w);
    }
#pragma unroll
    for (int o = 32; o; o >>= 1) tot += __shfl_xor(tot, o, 64);
    if (lane == 0) red[w] = tot;
    __syncthreads();
    const int offset = red[0] + red[1] + red[2] + red[3];

    // ---- own-chunk exclusive scan ----
    int i = b * 256 + t;
    int v = (i < N_NODES) ? cnt[i] : 0;
    int x = v;
#pragma unroll
    for (int o = 1; o < 64; o <<= 1) {
        int y = __shfl_up(x, o, 64);
        if (lane >= o) x += y;
    }
    if (lane == 63) wsum[w] = x;
    __syncthreads();
    int woff = 0;
#pragma unroll
    for (int j = 0; j < 4; ++j)
        if (j < w) woff += wsum[j];
    int excl = offset + woff + (x - v);
    if (i < N_NODES) { rowptr[i] = excl; pos[i] = excl; }
    if (i == N_NODES - 1) rowptr[N_NODES] = excl + v;
}

__global__ __launch_bounds__(256) void reorder_k(const int* __restrict__ esrc,
                                                 const int* __restrict__ edst,
                                                 int* __restrict__ pos,
                                                 int* __restrict__ ssrc) {
    int e = (blockIdx.x * 256 + threadIdx.x) * 4;
    if (e + 3 < N_EDGES) {
        int4 s = *(const int4*)(esrc + e);
        int4 d = *(const int4*)(edst + e);
        ssrc[atomicAdd(&pos[d.x], 1)] = s.x;
        ssrc[atomicAdd(&pos[d.y], 1)] = s.y;
        ssrc[atomicAdd(&pos[d.z], 1)] = s.z;
        ssrc[atomicAdd(&pos[d.w], 1)] = s.w;
    } else {
        for (; e < N_EDGES; ++e) {
            int p = atomicAdd(&pos[edst[e]], 1);
            ssrc[p] = esrc[e];
        }
    }
}

// ---------------------------------------------------------------------------
// K3: gather-aggregate, wide-load edition (round-6 proven).
// One wave per node (12500 blocks): the random-gather is latency-bound and
// NEEDS this high occupancy — round-12 showed folding it into the 2-block/CU
// fused kernel costs ~42 µs of exposed latency + 50 MB of L2 thrash.
// ---------------------------------------------------------------------------
__global__ __launch_bounds__(256) void aggregate_k(const short* __restrict__ nodesB,
                                                   const int* __restrict__ rowptr,
                                                   const int* __restrict__ ssrc,
                                                   short* __restrict__ aggB) {
    const int wid = threadIdx.x >> 6;
    const int lane = threadIdx.x & 63;
    const int g = lane >> 4, l = lane & 15;     // group 0..3, lane-in-group
    const int n = blockIdx.x * 4 + wid;
    if (n >= N_NODES) return;
    const int s0 = rowptr[n], s1 = rowptr[n + 1];

    float accf[8] = {0.f, 0.f, 0.f, 0.f, 0.f, 0.f, 0.f, 0.f};
    int e = s0 + g;
    for (; e + 4 < s1; e += 8) {                // 2 rows in flight per group
        int sa = ssrc[e], sb = ssrc[e + 4];
        bf16x8 va = *(const bf16x8*)(nodesB + (size_t)sa * DIM_H + l * 8);
        bf16x8 vb = *(const bf16x8*)(nodesB + (size_t)sb * DIM_H + l * 8);
#pragma unroll
        for (int k = 0; k < 8; ++k) accf[k] += bs2f(va[k]) + bs2f(vb[k]);
    }
    if (e < s1) {
        int sa = ssrc[e];
        bf16x8 va = *(const bf16x8*)(nodesB + (size_t)sa * DIM_H + l * 8);
#pragma unroll
        for (int k = 0; k < 8; ++k) accf[k] += bs2f(va[k]);
    }
#pragma unroll
    for (int k = 0; k < 8; ++k) {
        accf[k] += __shfl_xor(accf[k], 32, 64);
        accf[k] += __shfl_xor(accf[k], 16, 64);
    }
    if (g == 0) {
        uint4 ov;
        ov.x = pk2(accf[0], accf[1]);
        ov.y = pk2(accf[2], accf[3]);
        ov.z = pk2(accf[4], accf[5]);
        ov.w = pk2(accf[6], accf[7]);
        *(uint4*)(aggB + (size_t)n * DIM_H + l * 8) = ov;
    }
}

// ---------------------------------------------------------------------------
// K4: FULLY FUSED, wave-local, 8-wave / 128-row edition (round-8/10 proven).
// 16-row strips per wave, A operands in regs, double-buffered weight chunks,
// depth-1 prefetch, __syncthreads phases. No setprio (round-11: negative).
// ---------------------------------------------------------------------------
__global__ __launch_bounds__(512) void fused_k(const short* __restrict__ aggB,
                                               const short* __restrict__ nodesB,
                                               const short* __restrict__ wmsgB,
                                               const short* __restrict__ wihB,
                                               const short* __restrict__ whhB,
                                               const float* __restrict__ bmsg,
                                               const float* __restrict__ bih,
                                               const float* __restrict__ bhh,
                                               const int* __restrict__ deg,
                                               const float* __restrict__ colsum,
                                               const float* __restrict__ gamma,
                                               const float* __restrict__ beta,
                                               float* __restrict__ out) {
    __shared__ short Ms[128 * 128];       // msgin tile (wave-local 16-row strips)
    __shared__ short Wb[2][64 * 128];     // double-buffered weight chunk
    __shared__ float biasL[1280];         // bih|bhh|bmsg|cs|gamma|beta

    const int tid = threadIdx.x;
    const int lane = tid & 63, w = tid >> 6;        // w = 0..7
    const int m0 = blockIdx.x * 128;
    const int r16 = lane & 15, qh = lane >> 4;      // lane = 16*qh + r16
    const int wm = w * 16;                           // wave's 16-row strip
    const float invN = 1.0f / N_NODES;

    // ---- prologue A: biases -> LDS ----
    if (tid < 384) {
        biasL[tid]       = bih[tid];
        biasL[384 + tid] = bhh[tid];
    }
    if (tid < 128) {
        biasL[768  + tid] = bmsg[tid];
        biasL[896  + tid] = colsum[tid] * invN;
        biasL[1024 + tid] = gamma[tid];
        biasL[1152 + tid] = beta[tid];
    }

    // ---- prologue B: A-fragments (regs) + deg + stage chunk 0 ----
    bf16x8 aggF[4], nodF[4], msgF[4];
    const size_t rowA = (size_t)(m0 + wm + r16) * 128;
#pragma unroll
    for (int kt = 0; kt < 4; ++kt) {
        aggF[kt] = *(const bf16x8*)(aggB   + rowA + ((kt << 2) + qh) * 8);
        nodF[kt] = *(const bf16x8*)(nodesB + rowA + ((kt << 2) + qh) * 8);
    }
    int4 dgi = *(const int4*)(deg + m0 + wm + qh * 4);

    // weight chunk staging: 64 rows x 128 cols, XOR-swizzled 16B granules.
    // 8 waves x 2 dma16 each cover the 16 KB chunk.
#define STAGE_W(SRC, ROW0, BUF) do {                                         \
    _Pragma("unroll") for (int it = 0; it < 2; ++it) {                       \
        int c = w * 2 + it;                                                  \
        int s = c * 64 + lane;                                               \
        int r = s >> 4, q = s & 15;                                          \
        int g = q ^ (r & 15);                                                \
        dma16((SRC) + (((size_t)((ROW0) + r)) << 7) + (g << 3),              \
              &Wb[BUF][0] + (size_t)c * 512);                                \
    } } while (0)

    STAGE_W(wmsgB, 0, 0);                 // chunk 0

    f32x4 acc[2][4];
    unsigned rp[2][4][2], inp[2][4][2], np_[2][4][2];

#define CHUNK(BUF, AF, H, RST) do {                                          \
    _Pragma("unroll") for (int kt = 0; kt < 4; ++kt) {                       \
        const int sq = (((kt << 2) + qh) ^ r16) << 3;                        \
        bf16x8 b0 = *(const bf16x8*)&Wb[BUF][(r16     ) * 128 + sq];         \
        bf16x8 b1 = *(const bf16x8*)&Wb[BUF][(r16 + 16) * 128 + sq];         \
        bf16x8 b2 = *(const bf16x8*)&Wb[BUF][(r16 + 32) * 128 + sq];         \
        bf16x8 b3 = *(const bf16x8*)&Wb[BUF][(r16 + 48) * 128 + sq];         \
        f32x4 z4 = {0.f, 0.f, 0.f, 0.f};                                     \
        acc[H][0] = __builtin_amdgcn_mfma_f32_16x16x32_bf16(                 \
            AF[kt], b0, ((RST) && kt == 0) ? z4 : acc[H][0], 0, 0, 0);       \
        acc[H][1] = __builtin_amdgcn_mfma_f32_16x16x32_bf16(                 \
            AF[kt], b1, ((RST) && kt == 0) ? z4 : acc[H][1], 0, 0, 0);       \
        acc[H][2] = __builtin_amdgcn_mfma_f32_16x16x32_bf16(                 \
            AF[kt], b2, ((RST) && kt == 0) ? z4 : acc[H][2], 0, 0, 0);       \
        acc[H][3] = __builtin_amdgcn_mfma_f32_16x16x32_bf16(                 \
            AF[kt], b3, ((RST) && kt == 0) ? z4 : acc[H][3], 0, 0, 0);       \
    } } while (0)

    // ---------------- pipelined chunk sequence (round-4 schedule) ----------
    __syncthreads(); STAGE_W(wmsgB,  64, 1); CHUNK(0, aggF, 0, 1);   // c0
    __syncthreads(); STAGE_W(wihB,    0, 0); CHUNK(1, aggF, 1, 1);   // c1

    // EPI1: msgin = acc + deg*bmsg + colsum/N -> bf16 -> Ms, read back msgF
    {
        float dgf[4];
        dgf[0] = (m0 + wm + qh * 4 + 0 < N_NODES) ? (float)dgi.x : 0.f;
        dgf[1] = (m0 + wm + qh * 4 + 1 < N_NODES) ? (float)dgi.y : 0.f;
        dgf[2] = (m0 + wm + qh * 4 + 2 < N_NODES) ? (float)dgi.z : 0.f;
        dgf[3] = (m0 + wm + qh * 4 + 3 < N_NODES) ? (float)dgi.w : 0.f;
#pragma unroll
        for (int h = 0; h < 2; ++h)
#pragma unroll
            for (int j = 0; j < 4; ++j) {
                int c = h * 64 + j * 16 + r16;
                float bm = biasL[768 + c], cs = biasL[896 + c];
#pragma unroll
                for (int rr = 0; rr < 4; ++rr) {
                    int lr = wm + qh * 4 + rr;
                    float v = acc[h][j][rr] + dgf[rr] * bm + cs;
                    int slot = (c >> 3) ^ (lr & 15);
                    Ms[lr * 128 + slot * 8 + (c & 7)] = f2bs(v);
                }
            }
#pragma unroll
        for (int kt = 0; kt < 4; ++kt) {
            int kg = (kt << 2) + qh;
            msgF[kt] = *(const bf16x8*)&Ms[(wm + r16) * 128 + ((kg ^ r16) << 3)];
        }
    }

    __syncthreads(); STAGE_W(wihB,   64, 1); CHUNK(0, msgF, 0, 1);   // c2
    __syncthreads(); STAGE_W(whhB,    0, 0); CHUNK(1, msgF, 1, 1);   // c3
    __syncthreads(); STAGE_W(whhB,   64, 1); CHUNK(0, nodF, 0, 0);   // c4
    __syncthreads(); STAGE_W(wihB,  256, 0); CHUNK(1, nodF, 1, 0);   // c5
    // EPI2: r gate
#pragma unroll
    for (int h = 0; h < 2; ++h)
#pragma unroll
        for (int j = 0; j < 4; ++j) {
            int c = h * 64 + j * 16 + r16;
            float b0 = biasL[c] + biasL[384 + c];
            rp[h][j][0] = pk2(sigm(acc[h][j][0] + b0), sigm(acc[h][j][1] + b0));
            rp[h][j][1] = pk2(sigm(acc[h][j][2] + b0), sigm(acc[h][j][3] + b0));
        }

    __syncthreads(); STAGE_W(wihB,  320, 1); CHUNK(0, msgF, 0, 1);   // c6
    __syncthreads(); STAGE_W(whhB,  256, 0); CHUNK(1, msgF, 1, 1);   // c7
    // EPI3: i_n
#pragma unroll
    for (int h = 0; h < 2; ++h)
#pragma unroll
        for (int j = 0; j < 4; ++j) {
            int c = h * 64 + j * 16 + r16;
            float bi = biasL[256 + c];
            inp[h][j][0] = pk2(acc[h][j][0] + bi, acc[h][j][1] + bi);
            inp[h][j][1] = pk2(acc[h][j][2] + bi, acc[h][j][3] + bi);
        }

    __syncthreads(); STAGE_W(whhB,  320, 1); CHUNK(0, nodF, 0, 1);   // c8
    __syncthreads(); STAGE_W(wihB,  128, 0); CHUNK(1, nodF, 1, 1);   // c9
    // EPI4: n = tanh(i_n + r * h_n)
#pragma unroll
    for (int h = 0; h < 2; ++h)
#pragma unroll
        for (int j = 0; j < 4; ++j) {
            int c = h * 64 + j * 16 + r16;
            float bh = biasL[640 + c];
            float n0 = tanh_f(unlo(inp[h][j][0]) + unlo(rp[h][j][0]) * (acc[h][j][0] + bh));
            float n1 = tanh_f(unhi(inp[h][j][0]) + unhi(rp[h][j][0]) * (acc[h][j][1] + bh));
            float n2 = tanh_f(unlo(inp[h][j][1]) + unlo(rp[h][j][1]) * (acc[h][j][2] + bh));
            float n3 = tanh_f(unhi(inp[h][j][1]) + unhi(rp[h][j][1]) * (acc[h][j][3] + bh));
            np_[h][j][0] = pk2(n0, n1);
            np_[h][j][1] = pk2(n2, n3);
        }

    __syncthreads(); STAGE_W(wihB,  192, 1); CHUNK(0, msgF, 0, 1);   // c10
    __syncthreads(); STAGE_W(whhB,  128, 0); CHUNK(1, msgF, 1, 1);   // c11
    __syncthreads(); STAGE_W(whhB,  192, 1); CHUNK(0, nodF, 0, 0);   // c12
    __syncthreads();                         CHUNK(1, nodF, 1, 0);   // c13

    // EPI5: z; h' = (1-z)*n + z*h  (h from global bf16 nodes, L1-hot)
#pragma unroll
    for (int h = 0; h < 2; ++h)
#pragma unroll
        for (int j = 0; j < 4; ++j) {
            int c = h * 64 + j * 16 + r16;
            float b1 = biasL[128 + c] + biasL[512 + c];
#pragma unroll
            for (int rr = 0; rr < 4; ++rr) {
                int lr = wm + qh * 4 + rr;
                float hv = bs2f(nodesB[(size_t)(m0 + lr) * 128 + c]);
                float z = sigm(acc[h][j][rr] + b1);
                float nv = (rr & 1) ? unhi(np_[h][j][rr >> 1]) : unlo(np_[h][j][rr >> 1]);
                acc[h][j][rr] = (1.f - z) * nv + z * hv;   // acc := h_next
            }
        }

    // ---- LayerNorm (wave-local: each row lives in one 16-lane group) ----
#pragma unroll
    for (int rr = 0; rr < 4; ++rr) {
        float s = 0.f, q2 = 0.f;
#pragma unroll
        for (int h = 0; h < 2; ++h)
#pragma unroll
            for (int j = 0; j < 4; ++j) {
                float v = acc[h][j][rr];
                s += v; q2 += v * v;
            }
#pragma unroll
        for (int o = 1; o < 16; o <<= 1) {
            s  += __shfl_xor(s, o, 64);
            q2 += __shfl_xor(q2, o, 64);
        }
        int lr = wm + qh * 4 + rr;
        int gm = m0 + lr;
        float mu = s * (1.0f / DIM_H);
        float var = q2 * (1.0f / DIM_H) - mu * mu;
        float rstd = rsqrtf(var + 1e-5f);
        if (gm < N_NODES) {
#pragma unroll
            for (int h = 0; h < 2; ++h)
#pragma unroll
                for (int j = 0; j < 4; ++j) {
                    int c = h * 64 + j * 16 + r16;
                    int slot = (c >> 3) ^ (lr & 15);
                    float resid = bs2f(Ms[lr * 128 + slot * 8 + (c & 7)])
                                - biasL[896 + c];
                    out[(size_t)gm * DIM_H + c] =
                        biasL[1024 + c] * (acc[h][j][rr] - mu) * rstd
                        + biasL[1152 + c] + resid;
                }
        }
    }
#undef CHUNK
#undef STAGE_W
}

// ---------------------------------------------------------------------------
extern "C" void kernel_launch(void* const* d_in, const int* in_sizes, int n_in,
                              void* d_out, int out_size, void* d_ws, size_t ws_size,
                              hipStream_t stream) {
    const float* nodes = (const float*)d_in[0];
    const float* Wmsg  = (const float*)d_in[1];
    const float* bmsg  = (const float*)d_in[2];
    const float* wih   = (const float*)d_in[3];
    const float* whh   = (const float*)d_in[4];
    const float* bih   = (const float*)d_in[5];
    const float* bhh   = (const float*)d_in[6];
    const float* gamma = (const float*)d_in[7];
    const float* beta  = (const float*)d_in[8];
    const int* esrc = (const int*)d_in[9];
    const int* edst = (const int*)d_in[10];
    float* out = (float*)d_out;

    // workspace layout (~29 MB)
    char* ws = (char*)d_ws;
    short* aggB   = (short*)ws;                        // NPAD*256 B = 12,812,288
    short* nodesB = (short*)(ws + 12812288);           // 12,812,288
    short* wmsgB  = (short*)(ws + 25624576);           // 32 KB
    short* wihB   = (short*)(ws + 25657344);           // 96 KB
    short* whhB   = (short*)(ws + 25755648);           // 96 KB
    float* colsum = (float*)(ws + 25853952);           // 512 B
    int*   cnt    = (int*)(ws + 25854464);             // 200 KB (degree after hist)
    int*   rowptr = (int*)(ws + 26054464);             // 200 KB + pad
    int*   pos    = (int*)(ws + 26254480);             // 200 KB
    int*   ssrc   = (int*)(ws + 26454480);             // 2.4 MB -> end ~28.9 MB

    short* aggTail   = aggB   + (size_t)N_NODES * DIM_H;
    short* nodesTail = nodesB + (size_t)N_NODES * DIM_H;

    prep_k<<<NB_SCAN, 256, 0, stream>>>(Wmsg, wih, whh, wmsgB, wihB, whhB,
                                        cnt, colsum, aggTail, nodesTail);

    const int EB4 = (N_EDGES / 4 + 255) / 256;   // 586
    ch_k<<<EB4, 256, 0, stream>>>(nodes, colsum, nodesB, edst, cnt);
    scan_k<<<NB_SCAN, 256, 0, stream>>>(cnt, rowptr, pos);
    reorder_k<<<EB4, 256, 0, stream>>>(esrc, edst, pos, ssrc);
    aggregate_k<<<(N_NODES + 3) / 4, 256, 0, stream>>>(nodesB, rowptr, ssrc, aggB);

    const int MB = (N_NODES + 127) / 128;   // 391
    fused_k<<<MB, 512, 0, stream>>>(aggB, nodesB, wmsgB, wihB, whhB,
                                    bmsg, bih, bhh, cnt, colsum, gamma, beta, out);
}